// Round 6
// baseline (222.062 us; speedup 1.0000x reference)
//
#include <hip/hip_runtime.h>
#include <stdint.h>
#include <math.h>

static constexpr int TOPK  = 8;
static constexpr int TOPKG = 4;
static constexpr int NEXP  = 256;
static constexpr float RSF = 2.5f;
static constexpr int ILP   = 4;     // tokens per wave (independent chains)

// DPP control codes
static constexpr int DPP_QX1 = 0xB1;  // quad_perm [1,0,3,2]  == xor1
static constexpr int DPP_QX2 = 0x4E;  // quad_perm [2,3,0,1]  == xor2
static constexpr int DPP_HM  = 0x141; // row_half_mirror      == xor4 once quads uniform
static constexpr int DPP_MIR = 0x140; // row_mirror           == xor8 once 8-blocks uniform
static constexpr int DPP_B15 = 0x142; // row_bcast15
static constexpr int DPP_B31 = 0x143; // row_bcast31

// old = src so unwritten lanes keep their own value (safe for max/add trees)
template <int CTRL>
__device__ __forceinline__ float dppmov(float x) {
    int xi = __float_as_int(x);
    return __int_as_float(__builtin_amdgcn_update_dpp(xi, xi, CTRL, 0xF, 0xF, false));
}

// descending compare-exchange with index payload
__device__ __forceinline__ void cas(float& ax, float& ay, int& ix, int& iy) {
    bool p   = ax < ay;
    float hi = fmaxf(ax, ay), lo = fminf(ax, ay);
    int   nx = p ? iy : ix,   ny = p ? ix : iy;
    ax = hi; ay = lo; ix = nx; iy = ny;
}

__global__ __launch_bounds__(256) void router_kernel(
    const float* __restrict__ logits,   // [T, 256]
    const float* __restrict__ bias,     // [256]
    float* __restrict__ out_w,          // [T, 8]
    float* __restrict__ out_id,         // [T, 8] (ids as float)
    int T)
{
    const int lane = threadIdx.x & 63;
    const int wid  = threadIdx.x >> 6;
    const int t0   = (blockIdx.x * (int)(blockDim.x >> 6) + wid) * ILP;
    if (t0 >= T) return;

    float4 b = ((const float4*)bias)[lane];   // shared across the 4 tokens

    int  tt[ILP];
    bool act[ILP];
    float4 v[ILP];
    #pragma unroll
    for (int u = 0; u < ILP; ++u) {
        act[u] = (t0 + u) < T;
        tt[u]  = act[u] ? (t0 + u) : 0;
        v[u]   = ((const float4*)(logits + (size_t)tt[u] * NEXP))[lane];
    }

    const float NEG   = -INFINITY;
    const int   ebase = lane << 2;
    const int   g     = lane >> 3;
    const int   j     = lane & 7;

    float a0[ILP], a1[ILP], a2[ILP], a3[ILP];
    uint32_t ipack[ILP];
    int i0cur[ILP];

    #pragma unroll
    for (int u = 0; u < ILP; ++u) {
        float s0 = v[u].x + b.x;
        float s1 = v[u].y + b.y;
        float s2 = v[u].z + b.z;
        float s3 = v[u].w + b.w;

        // group score: sum of top-2 biased scores per 8-lane (32-expert) group
        float hi01 = fmaxf(s0, s1), lo01 = fminf(s0, s1);
        float hi23 = fmaxf(s2, s3), lo23 = fminf(s2, s3);
        float m1 = fmaxf(hi01, hi23);
        float m2 = fmaxf(fminf(hi01, hi23), fmaxf(lo01, lo23));
        {
            float o1 = dppmov<DPP_QX1>(m1), o2 = dppmov<DPP_QX1>(m2);
            float n1 = fmaxf(m1, o1);
            float n2 = fmaxf(fminf(m1, o1), fmaxf(m2, o2));
            m1 = n1; m2 = n2;
        }
        {
            float o1 = dppmov<DPP_QX2>(m1), o2 = dppmov<DPP_QX2>(m2);
            float n1 = fmaxf(m1, o1);
            float n2 = fmaxf(fminf(m1, o1), fmaxf(m2, o2));
            m1 = n1; m2 = n2;
        }
        {
            float o1 = dppmov<DPP_HM>(m1), o2 = dppmov<DPP_HM>(m2);
            float n1 = fmaxf(m1, o1);
            float n2 = fmaxf(fminf(m1, o1), fmaxf(m2, o2));
            m1 = n1; m2 = n2;
        }
        const float gscore = m1 + m2;   // uniform within each 8-lane group

        // group rank: shuffle-transpose + ballot + byte popcount (exact tie-break)
        float gj = __shfl(gscore, j << 3, 64);
        bool beats = (gj > gscore) || (gj == gscore && j < g);
        uint64_t bal = __ballot(beats);
        int rank = __popcll(bal & (0xFFull << (g << 3)));
        const bool sel = (rank < TOPKG);

        // mask to -inf outside selected groups; sort lane's 4 (val,idx) desc
        float x0 = sel ? s0 : NEG;
        float x1 = sel ? s1 : NEG;
        float x2 = sel ? s2 : NEG;
        float x3 = sel ? s3 : NEG;
        int i0 = ebase, i1 = ebase + 1, i2 = ebase + 2, i3 = ebase + 3;
        cas(x0, x1, i0, i1);
        cas(x2, x3, i2, i3);
        cas(x0, x2, i0, i2);
        cas(x1, x3, i1, i3);
        cas(x1, x2, i1, i2);
        a0[u] = x0; a1[u] = x1; a2[u] = x2; a3[u] = x3;
        ipack[u] = (uint32_t)i0 | ((uint32_t)i1 << 8) |
                   ((uint32_t)i2 << 16) | ((uint32_t)i3 << 24);
        i0cur[u] = i0;
    }

    int   myid[ILP];
    float myw [ILP];
    #pragma unroll
    for (int u = 0; u < ILP; ++u) { myid[u] = 0; myw[u] = 0.f; }

    #pragma unroll
    for (int r = 0; r < TOPK; ++r) {
        #pragma unroll
        for (int u = 0; u < ILP; ++u) {
            // wave max of heads, accumulating toward lane 63
            float x = a0[u];
            x = fmaxf(x, dppmov<DPP_QX1>(x));
            x = fmaxf(x, dppmov<DPP_QX2>(x));
            x = fmaxf(x, dppmov<DPP_HM >(x));
            x = fmaxf(x, dppmov<DPP_MIR>(x));
            x = fmaxf(x, dppmov<DPP_B15>(x));
            x = fmaxf(x, dppmov<DPP_B31>(x));
            const float smax = __int_as_float(
                __builtin_amdgcn_readlane(__float_as_int(x), 63));     // scalar

            uint64_t wb  = __ballot(a0[u] == smax);                    // 1 v_cmp
            const int wl = __ffsll((unsigned long long)wb) - 1;        // scalar lane
            const int idx = __builtin_amdgcn_readlane(i0cur[u], wl);   // scalar id

            const bool mine = (lane == r);
            myid[u] = mine ? idx  : myid[u];
            myw [u] = mine ? smax : myw[u];

            // winner lane shifts its sorted list up
            const bool win = (lane == wl);
            a0[u] = win ? a1[u] : a0[u];
            a1[u] = win ? a2[u] : a1[u];
            a2[u] = win ? a3[u] : a2[u];
            a3[u] = win ? NEG   : a3[u];
            ipack[u] = win ? (ipack[u] >> 8) : ipack[u];
            i0cur[u] = (int)(ipack[u] & 255u);
        }
    }

    // epilogue: unbias via L1-hot bias gather, 8-lane sum, store
    #pragma unroll
    for (int u = 0; u < ILP; ++u) {
        float bi = 0.f;
        if (lane < TOPK) bi = bias[myid[u]];
        float w = myw[u] - bi;                  // lanes >= 8: 0 - 0 = 0
        float t = w;
        t += dppmov<DPP_QX1>(t);
        t += dppmov<DPP_QX2>(t);
        t += dppmov<DPP_HM >(t);                // lanes 0..7 hold the 8-sum

        if (act[u] && lane < TOPK) {
            out_w [(size_t)tt[u] * TOPK + lane] = w / t * RSF;
            out_id[(size_t)tt[u] * TOPK + lane] = (float)myid[u];
        }
    }
}

extern "C" void kernel_launch(void* const* d_in, const int* in_sizes, int n_in,
                              void* d_out, int out_size, void* d_ws, size_t ws_size,
                              hipStream_t stream) {
    const float* logits = (const float*)d_in[0];
    const float* bias   = (const float*)d_in[1];
    const int T = in_sizes[0] / NEXP;   // 131072
    float* out = (float*)d_out;
    float* out_w  = out;
    float* out_id = out + (size_t)T * TOPK;

    const int waves_per_block  = 256 / 64;
    const int tokens_per_block = waves_per_block * ILP;     // 16
    const int blocks = (T + tokens_per_block - 1) / tokens_per_block;
    router_kernel<<<blocks, 256, 0, stream>>>(logits, bias, out_w, out_id, T);
}

// Round 8
// 206.530 us; speedup vs baseline: 1.0752x; 1.0752x over previous
//
#include <hip/hip_runtime.h>
#include <stdint.h>
#include <math.h>

static constexpr int TOPK  = 8;
static constexpr int TOPKG = 4;
static constexpr int NEXP  = 256;
static constexpr float RSF = 2.5f;

// DPP control codes
static constexpr int DPP_QX1 = 0xB1;  // quad_perm [1,0,3,2]  == xor1
static constexpr int DPP_QX2 = 0x4E;  // quad_perm [2,3,0,1]  == xor2
static constexpr int DPP_HM  = 0x141; // row_half_mirror      == xor4 once quads uniform
static constexpr int DPP_MIR = 0x140; // row_mirror           == xor8 once 8-blocks uniform

template <int CTRL>
__device__ __forceinline__ float dppmov_f(float x) {
    int xi = __float_as_int(x);
    return __int_as_float(__builtin_amdgcn_update_dpp(xi, xi, CTRL, 0xF, 0xF, false));
}
template <int CTRL>
__device__ __forceinline__ uint32_t dppmov_u(uint32_t x) {
    return (uint32_t)__builtin_amdgcn_update_dpp((int)x, (int)x, CTRL, 0xF, 0xF, false);
}

// monotonic f32 -> u32 (order-preserving, bijective)
__device__ __forceinline__ uint32_t f2sort(float f) {
    uint32_t u = __float_as_uint(f);
    return u ^ ((uint32_t)((int32_t)u >> 31) | 0x80000000u);
}

// descending compare-exchange (u32 keys) with index payload; stable on ties
__device__ __forceinline__ void cas(uint32_t& ax, uint32_t& ay, int& ix, int& iy) {
    bool p      = ax < ay;
    uint32_t hi = p ? ay : ax, lo = p ? ax : ay;
    int nx      = p ? iy : ix,  ny = p ? ix : iy;
    ax = hi; ay = lo; ix = nx; iy = ny;
}

__global__ __launch_bounds__(256) void router_kernel(
    const float* __restrict__ logits,   // [T, 256]
    const float* __restrict__ bias,     // [256]
    float* __restrict__ out_w,          // [T, 8]
    float* __restrict__ out_id,         // [T, 8] (ids as float)
    int T)
{
    const int lane  = threadIdx.x & 63;
    const int token = blockIdx.x * (blockDim.x >> 6) + (threadIdx.x >> 6);
    if (token >= T) return;

    const float* row = logits + (size_t)token * NEXP;
    float4 v = ((const float4*)row)[lane];
    float4 b = ((const float4*)bias)[lane];

    float s0 = v.x + b.x;
    float s1 = v.y + b.y;
    float s2 = v.z + b.z;
    float s3 = v.w + b.w;

    // ---- group score: sum of top-2 biased scores per 8-lane (32-expert) group ----
    float hi01 = fmaxf(s0, s1), lo01 = fminf(s0, s1);
    float hi23 = fmaxf(s2, s3), lo23 = fminf(s2, s3);
    float m1 = fmaxf(hi01, hi23);
    float m2 = fmaxf(fminf(hi01, hi23), fmaxf(lo01, lo23));
    {
        float o1 = dppmov_f<DPP_QX1>(m1), o2 = dppmov_f<DPP_QX1>(m2);
        float n1 = fmaxf(m1, o1);
        float n2 = fmaxf(fminf(m1, o1), fmaxf(m2, o2));
        m1 = n1; m2 = n2;
    }
    {
        float o1 = dppmov_f<DPP_QX2>(m1), o2 = dppmov_f<DPP_QX2>(m2);
        float n1 = fmaxf(m1, o1);
        float n2 = fmaxf(fminf(m1, o1), fmaxf(m2, o2));
        m1 = n1; m2 = n2;
    }
    {
        float o1 = dppmov_f<DPP_HM>(m1), o2 = dppmov_f<DPP_HM>(m2);
        float n1 = fmaxf(m1, o1);
        float n2 = fmaxf(fminf(m1, o1), fmaxf(m2, o2));
        m1 = n1; m2 = n2;
    }
    const float gscore = m1 + m2;   // uniform within each 8-lane group

    // ---- group rank: shuffle-transpose + ballot + windowed popcount ----
    const int g = lane >> 3;
    const int j = lane & 7;
    float gj = __shfl(gscore, j << 3, 64);
    bool beats = (gj > gscore) || (gj == gscore && j < g);
    uint64_t balg = __ballot(beats);
    int rank = __popcll(balg & (0xFFull << (g << 3)));
    const bool sel = (rank < TOPKG);

    // ---- sortable keys (masked -> 0), per-lane descending sort of 4 ----
    uint32_t a0 = sel ? f2sort(s0) : 0u;
    uint32_t a1 = sel ? f2sort(s1) : 0u;
    uint32_t a2 = sel ? f2sort(s2) : 0u;
    uint32_t a3 = sel ? f2sort(s3) : 0u;
    const int ebase = lane << 2;
    int i0 = ebase, i1 = ebase + 1, i2 = ebase + 2, i3 = ebase + 3;
    cas(a0, a1, i0, i1);
    cas(a2, a3, i2, i3);
    cas(a0, a2, i0, i2);
    cas(a1, a3, i1, i3);
    cas(a1, a2, i1, i2);
    uint32_t ipack = (uint32_t)i0 | ((uint32_t)i1 << 8) |
                     ((uint32_t)i2 << 16) | ((uint32_t)i3 << 24);

    // ---- init per-16-block head maxima (SGPR-cached) ----
    uint32_t bm = a0;
    bm = max(bm, dppmov_u<DPP_QX1>(bm));
    bm = max(bm, dppmov_u<DPP_QX2>(bm));
    bm = max(bm, dppmov_u<DPP_HM >(bm));
    bm = max(bm, dppmov_u<DPP_MIR>(bm));          // block-of-16 max in all its lanes
    uint32_t rm0 = (uint32_t)__builtin_amdgcn_readlane((int)bm,  0);
    uint32_t rm1 = (uint32_t)__builtin_amdgcn_readlane((int)bm, 16);
    uint32_t rm2 = (uint32_t)__builtin_amdgcn_readlane((int)bm, 32);
    uint32_t rm3 = (uint32_t)__builtin_amdgcn_readlane((int)bm, 48);

    int myid = 0;
    #pragma unroll
    for (int r = 0; r < TOPK; ++r) {
        // scalar wave max from cached block maxima (zero VALU latency)
        const uint32_t smax = max(max(rm0, rm1), max(rm2, rm3));

        const uint64_t bal = __ballot(a0 == smax);                  // single v_cmp
        const int wl  = __ffsll((unsigned long long)bal) - 1;       // scalar lane
        const int idx = __builtin_amdgcn_readlane((int)ipack, wl) & 255; // scalar

        myid = (lane == r) ? idx : myid;

        // EXACTLY ONE lane retires (lowest tied lane) — required for exact-tie
        // correctness: on ties, remaining copies are picked in later rounds
        // in index order, matching jax.lax.top_k. (R7 bug: a0==smax retired all.)
        const bool win = (lane == wl);
        a0 = win ? a1 : a0;
        a1 = win ? a2 : a1;
        a2 = win ? a3 : a2;
        a3 = win ? 0u : a3;
        ipack = win ? (ipack >> 8) : ipack;

        // refresh the winner block's cached max (off the critical head)
        uint32_t nb = a0;
        nb = max(nb, dppmov_u<DPP_QX1>(nb));
        nb = max(nb, dppmov_u<DPP_QX2>(nb));
        nb = max(nb, dppmov_u<DPP_HM >(nb));
        nb = max(nb, dppmov_u<DPP_MIR>(nb));
        const uint32_t nbm = (uint32_t)__builtin_amdgcn_readlane((int)nb, wl);
        const int blk = wl >> 4;                              // scalar
        rm0 = (blk == 0) ? nbm : rm0;
        rm1 = (blk == 1) ? nbm : rm1;
        rm2 = (blk == 2) ? nbm : rm2;
        rm3 = (blk == 3) ? nbm : rm3;
    }

    // ---- epilogue: exact unbiased gather (L1-hot), 8-lane sum, store ----
    float w = 0.f;
    if (lane < TOPK) w = row[myid];
    float t = w;
    t += dppmov_f<DPP_QX1>(t);
    t += dppmov_f<DPP_QX2>(t);
    t += dppmov_f<DPP_HM >(t);                    // lanes 0..7 hold the 8-sum

    if (lane < TOPK) {
        out_w [(size_t)token * TOPK + lane] = w / t * RSF;
        out_id[(size_t)token * TOPK + lane] = (float)myid;
    }
}

extern "C" void kernel_launch(void* const* d_in, const int* in_sizes, int n_in,
                              void* d_out, int out_size, void* d_ws, size_t ws_size,
                              hipStream_t stream) {
    const float* logits = (const float*)d_in[0];
    const float* bias   = (const float*)d_in[1];
    const int T = in_sizes[0] / NEXP;   // 131072
    float* out = (float*)d_out;
    float* out_w  = out;
    float* out_id = out + (size_t)T * TOPK;

    const int waves_per_block = 256 / 64;
    const int blocks = (T + waves_per_block - 1) / waves_per_block;
    router_kernel<<<blocks, 256, 0, stream>>>(logits, bias, out_w, out_id, T);
}